// Round 4
// baseline (1031.499 us; speedup 1.0000x reference)
//
#include <hip/hip_runtime.h>
#include <hip/hip_bf16.h>
#include <stdint.h>

#define N_NODES 100000
#define IN_CH   128
#define HID     128
#define OUT_CH  64
#define N_EDGES 1600000

#define NB    196      // buckets of 512 nodes
#define NBLK  250      // edge-partition blocks for phases A/B
#define EPB   6400     // edges per block
#define NCHUNK 782     // 128-node chunks for sliced agg

typedef __attribute__((ext_vector_type(8))) short  bf16x8;
typedef __attribute__((ext_vector_type(4))) float  f32x4;

// ---------------- helpers ----------------

__device__ __forceinline__ unsigned short f2bf(float f) {   // RNE f32->bf16
    unsigned int u = __float_as_uint(f);
    u = (u + 0x7fffu + ((u >> 16) & 1u)) >> 16;
    return (unsigned short)u;
}
__device__ __forceinline__ float bfl(unsigned int u) { return __uint_as_float(u << 16); }
__device__ __forceinline__ float bfh(unsigned int u) { return __uint_as_float(u & 0xffff0000u); }

// ---------------- CSR build: bucket sort ----------------

__global__ __launch_bounds__(256) void k_phaseA(const int* __restrict__ dst,
                                                int* __restrict__ Cm) {
    __shared__ int hist[NB];
    int blk = blockIdx.x, t = threadIdx.x;
    if (t < NB) hist[t] = 0;
    __syncthreads();
    int base = blk * EPB;
#pragma unroll 5
    for (int k = 0; k < EPB / 256; k++) {
        int d = dst[base + k * 256 + t];
        atomicAdd(&hist[d >> 9], 1);
    }
    __syncthreads();
    if (t < NB) Cm[blk * NB + t] = hist[t];
}

// parallel scan of Cm over blocks: one block per bucket
__global__ __launch_bounds__(256) void k_scanBkt(int* __restrict__ Cm,
                                                 int* __restrict__ bktSum) {
    __shared__ int sdata[256];
    int b = blockIdx.x, t = threadIdx.x;
    int v = (t < NBLK) ? Cm[t * NB + b] : 0;
    sdata[t] = v;
    __syncthreads();
    int val = v;
    for (int off = 1; off < 256; off <<= 1) {
        int tmp = (t >= off) ? sdata[t - off] : 0;
        __syncthreads();
        val += tmp;
        sdata[t] = val;
        __syncthreads();
    }
    if (t < NBLK) Cm[t * NB + b] = val - v;   // exclusive prefix within bucket
    if (t == 255) bktSum[b] = val;
}

__global__ __launch_bounds__(256) void k_scanBase(const int* __restrict__ bktSum,
                                                  int* __restrict__ bktBase) {
    __shared__ int sdata[256];
    int t = threadIdx.x;
    int v = (t < NB) ? bktSum[t] : 0;
    sdata[t] = v;
    __syncthreads();
    int val = v;
    for (int off = 1; off < 256; off <<= 1) {
        int tmp = (t >= off) ? sdata[t - off] : 0;
        __syncthreads();
        val += tmp;
        sdata[t] = val;
        __syncthreads();
    }
    if (t < NB) bktBase[t] = val - v;
    if (t == 0) bktBase[NB] = N_EDGES;
}

__global__ __launch_bounds__(256) void k_phaseB(const int* __restrict__ src,
                                                const int* __restrict__ dst,
                                                const int* __restrict__ Cm,
                                                const int* __restrict__ bktBase,
                                                unsigned int* __restrict__ bucketed) {
    __shared__ int offs[NB];
    int blk = blockIdx.x, t = threadIdx.x;
    if (t < NB) offs[t] = Cm[blk * NB + t] + bktBase[t];
    __syncthreads();
    int base = blk * EPB;
#pragma unroll 5
    for (int k = 0; k < EPB / 256; k++) {
        int e = base + k * 256 + t;
        int d = dst[e];
        int sv = src[e];
        int pos = atomicAdd(&offs[d >> 9], 1);
        bucketed[pos] = ((unsigned int)sv << 9) | (unsigned int)(d & 511);
    }
}

__global__ __launch_bounds__(512) void k_phaseC(const unsigned int* __restrict__ bucketed,
                                                const int* __restrict__ bktBase,
                                                int* __restrict__ rowptr,
                                                float* __restrict__ dinvg,
                                                int* __restrict__ csr_src) {
    __shared__ int cnt[512];
    __shared__ int cur[512];
    __shared__ int sdata[512];
    int b = blockIdx.x, t = threadIdx.x;
    int base = bktBase[b], endR = bktBase[b + 1];
    int nodeBase = b << 9;
    int nNodes = N_NODES - nodeBase;
    if (nNodes > 512) nNodes = 512;

    cnt[t] = 0;
    __syncthreads();
    for (int e = base + t; e < endR; e += 512)
        atomicAdd(&cnt[bucketed[e] & 511], 1);
    __syncthreads();

    int s = cnt[t];
    sdata[t] = s;
    __syncthreads();
    int val = s;
    for (int off = 1; off < 512; off <<= 1) {
        int tmp = (t >= off) ? sdata[t - off] : 0;
        __syncthreads();
        val += tmp;
        sdata[t] = val;
        __syncthreads();
    }
    cur[t] = val - s;
    if (t < nNodes) {
        rowptr[nodeBase + t] = base + val - s;
        dinvg[nodeBase + t] = rsqrtf((float)s + 1.0f);
    }
    if (b == NB - 1 && t == 0) rowptr[N_NODES] = N_EDGES;
    __syncthreads();

    for (int e = base + t; e < endR; e += 512) {
        unsigned int u = bucketed[e];
        int pos = base + atomicAdd(&cur[u & 511], 1);
        csr_src[pos] = (int)(u >> 9);
    }
}

// ---------------- W prep: transpose to bf16 [n][k], fuse mu|ls concat -------
// Also zeroes the sliced-agg work counters (16 ints) each launch/replay.

__global__ __launch_bounds__(256) void k_prepW(const float* __restrict__ W1,
                                               const float* __restrict__ Wmu,
                                               const float* __restrict__ Wls,
                                               unsigned short* __restrict__ Wt1,
                                               unsigned short* __restrict__ WtC,
                                               int* __restrict__ ctr) {
    int idx = blockIdx.x * 256 + threadIdx.x;
    if (blockIdx.x == 0 && threadIdx.x < 16) ctr[threadIdx.x] = 0;
    int n = idx >> 7, k = idx & 127;
    Wt1[idx] = f2bf(W1[k * 128 + n]);
    WtC[idx] = f2bf((n < 64) ? Wmu[k * 64 + n] : Wls[k * 64 + (n - 64)]);
}

// ------ MFMA GEMM1: h0' = dinv*(x@W1), SLICE-MAJOR bf16 [slice][node][16] ---
// slice = nt (output col block of 16), channel-in-slice = lm.

#define LDA 136

__global__ __launch_bounds__(256) void k_gemm1(const float* __restrict__ X,
                                               const unsigned short* __restrict__ Wt,
                                               const float* __restrict__ dinv,
                                               unsigned short* __restrict__ Y) {
    __shared__ unsigned short sA[128 * LDA];
    int t = threadIdx.x;
    int R0 = blockIdx.x * 128;
    int row = t >> 1, colb = (t & 1) * 64;
    bool valid = (R0 + row) < N_NODES;
    const float* Xr = X + (size_t)(R0 + row) * 128 + colb;
    unsigned short* dp = sA + row * LDA + colb;
#pragma unroll
    for (int j = 0; j < 16; j++) {
        float4 v = valid ? *(const float4*)(Xr + j * 4) : make_float4(0.f, 0.f, 0.f, 0.f);
        ushort4 o;
        o.x = f2bf(v.x); o.y = f2bf(v.y); o.z = f2bf(v.z); o.w = f2bf(v.w);
        *(ushort4*)(dp + j * 4) = o;
    }
    __syncthreads();

    int wv = t >> 6, l = t & 63;
    int quad = l >> 4, lm = l & 15;

    bf16x8 a[2][4];
#pragma unroll
    for (int mt = 0; mt < 2; mt++)
#pragma unroll
        for (int ks = 0; ks < 4; ks++)
            a[mt][ks] = *(const bf16x8*)(sA + (wv * 32 + mt * 16 + lm) * LDA +
                                         ks * 32 + quad * 8);

    f32x4 acc[2][8] = {};
#pragma unroll
    for (int nt = 0; nt < 8; nt++) {
        bf16x8 b[4];
        const unsigned short* Wp = Wt + (nt * 16 + lm) * 128 + quad * 8;
#pragma unroll
        for (int ks = 0; ks < 4; ks++)
            b[ks] = *(const bf16x8*)(Wp + ks * 32);
#pragma unroll
        for (int mt = 0; mt < 2; mt++) {
            f32x4 c = acc[mt][nt];
#pragma unroll
            for (int ks = 0; ks < 4; ks++)
                c = __builtin_amdgcn_mfma_f32_16x16x32_bf16(a[mt][ks], b[ks], c, 0, 0, 0);
            acc[mt][nt] = c;
        }
    }

    int rbase = R0 + wv * 32 + quad * 4;
    float dv[2][4];
#pragma unroll
    for (int mt = 0; mt < 2; mt++)
#pragma unroll
        for (int reg = 0; reg < 4; reg++) {
            int r = rbase + mt * 16 + reg;
            dv[mt][reg] = (r < N_NODES) ? dinv[r] : 0.f;
        }
#pragma unroll
    for (int mt = 0; mt < 2; mt++)
#pragma unroll
        for (int nt = 0; nt < 8; nt++)
#pragma unroll
            for (int reg = 0; reg < 4; reg++) {
                int r = rbase + mt * 16 + reg;
                if (r < N_NODES)
                    Y[((size_t)nt * N_NODES + r) * 16 + lm] =
                        f2bf(acc[mt][nt][reg] * dv[mt][reg]);
            }
}

// ------------- physically XCD-pinned sliced aggregation ---------------------
// Each block reads HW_REG_XCC_ID and claims 128-node chunks of ITS OWN XCD's
// 16-channel slice (3.2 MB -> L2-resident) via per-slice atomic queues; an
// 8-slice steal sweep guarantees completion for any dispatch (G16).
// Inputs pre-scaled (h' = d*h): agg_i = d_i*(h'_i + sum_j h'_j), weight 1.
// Wave = 1 node; lane l: edge slot j=l>>3 (16 edges in flight), 4B of the
// 32-B slice row at cl=l&7. 3-step shfl_xor reduce over j; j==0 lanes store.
// LAYER 1: out = sliced hb' = d*relu(d*agg+b1) (same-XCD L2 stays warm for
// the layer-2 gather).  LAYER 2: out = node-major g for gemm2.

template<int LAYER>
__global__ __launch_bounds__(256, 8) void k_aggx(const unsigned short* __restrict__ Hin,
                                                 const int* __restrict__ rowptr,
                                                 const int* __restrict__ csr_src,
                                                 const float* __restrict__ dinv,
                                                 const float* __restrict__ bias,
                                                 unsigned short* __restrict__ Hout,
                                                 int* __restrict__ ctr) {
    __shared__ int s_c;
    int t = threadIdx.x;
    int w = t >> 6, l = t & 63;
    int j = l >> 3, cl = l & 7;
    unsigned int xcd;
    asm volatile("s_getreg_b32 %0, hwreg(HW_REG_XCC_ID)" : "=s"(xcd));
    xcd &= 7u;
    int* bc = ctr + (LAYER == 1 ? 0 : 8);

    for (int ss = 0; ss < 8; ss++) {
        int slice = (int)((xcd + (unsigned)ss) & 7u);
        const unsigned short* Hs = Hin + (size_t)slice * ((size_t)N_NODES * 16);
        int* cp = bc + slice;
        for (;;) {
            __syncthreads();
            if (t == 0) s_c = atomicAdd(cp, 1);
            __syncthreads();
            int c = s_c;
            if (c >= NCHUNK) break;
            int nb = c * 128 + w * 32;
            for (int n0 = 0; n0 < 32; n0++) {
                int node = nb + n0;
                if (node >= N_NODES) break;
                node = __builtin_amdgcn_readfirstlane(node);
                int beg = rowptr[node], end = rowptr[node + 1];
                float di = dinv[node];
                unsigned int r0 = *(const unsigned int*)(Hs + (size_t)node * 16 + cl * 2);
                float a0 = (j == 0) ? bfl(r0) : 0.f;
                float a1 = (j == 0) ? bfh(r0) : 0.f;
                for (int p = beg; p < end; p += 16) {
                    int q0 = p + j, q1 = p + 8 + j;
                    int c0 = q0 < end ? q0 : end - 1;
                    int c1 = q1 < end ? q1 : end - 1;
                    int s0 = __builtin_nontemporal_load(csr_src + c0);
                    int s1 = __builtin_nontemporal_load(csr_src + c1);
                    unsigned int v0 = *(const unsigned int*)(Hs + (size_t)s0 * 16 + cl * 2);
                    unsigned int v1 = *(const unsigned int*)(Hs + (size_t)s1 * 16 + cl * 2);
                    if (q0 < end) { a0 += bfl(v0); a1 += bfh(v0); }
                    if (q1 < end) { a0 += bfl(v1); a1 += bfh(v1); }
                }
                a0 += __shfl_xor(a0, 8);  a1 += __shfl_xor(a1, 8);
                a0 += __shfl_xor(a0, 16); a1 += __shfl_xor(a1, 16);
                a0 += __shfl_xor(a0, 32); a1 += __shfl_xor(a1, 32);
                if (j == 0) {
                    if (LAYER == 1) {
                        float2 bv = *(const float2*)(bias + slice * 16 + cl * 2);
                        a0 = a0 * di + bv.x;
                        a1 = a1 * di + bv.y;
                        a0 = a0 > 0.f ? a0 : 0.f;
                        a1 = a1 > 0.f ? a1 : 0.f;
                        a0 *= di; a1 *= di;          // pre-scale for layer-2 gather
                        unsigned int o = ((unsigned int)f2bf(a1) << 16) | (unsigned int)f2bf(a0);
                        *(unsigned int*)(Hout + ((size_t)slice * N_NODES + node) * 16 + cl * 2) = o;
                    } else {
                        a0 *= di; a1 *= di;
                        unsigned int o = ((unsigned int)f2bf(a1) << 16) | (unsigned int)f2bf(a0);
                        __builtin_nontemporal_store(o,
                            (unsigned int*)(Hout + (size_t)node * 128 + slice * 16 + cl * 2));
                    }
                }
            }
        }
    }
}

// ---------------- MFMA GEMM2: g[bf16 node-major] @ WtC + bias -> out --------

__global__ __launch_bounds__(256) void k_gemm2(const unsigned short* __restrict__ G,
                                               const unsigned short* __restrict__ Wt,
                                               const float* __restrict__ bmu,
                                               const float* __restrict__ bls,
                                               float* __restrict__ out) {
    __shared__ unsigned short sA[128 * LDA];
    int t = threadIdx.x;
    int R0 = blockIdx.x * 128;
    int row = t >> 1, colb = (t & 1) * 64;
    bool valid = (R0 + row) < N_NODES;
    const unsigned short* Gr = G + (size_t)(R0 + row) * 128 + colb;
    unsigned short* dp = sA + row * LDA + colb;
#pragma unroll
    for (int j = 0; j < 8; j++) {
        bf16x8 v = {0, 0, 0, 0, 0, 0, 0, 0};
        if (valid) v = *(const bf16x8*)(Gr + j * 8);
        *(bf16x8*)(dp + j * 8) = v;
    }
    __syncthreads();

    int wv = t >> 6, l = t & 63;
    int quad = l >> 4, lm = l & 15;

    bf16x8 a[2][4];
#pragma unroll
    for (int mt = 0; mt < 2; mt++)
#pragma unroll
        for (int ks = 0; ks < 4; ks++)
            a[mt][ks] = *(const bf16x8*)(sA + (wv * 32 + mt * 16 + lm) * LDA +
                                         ks * 32 + quad * 8);

    f32x4 acc[2][8] = {};
#pragma unroll
    for (int nt = 0; nt < 8; nt++) {
        bf16x8 b[4];
        const unsigned short* Wp = Wt + (nt * 16 + lm) * 128 + quad * 8;
#pragma unroll
        for (int ks = 0; ks < 4; ks++)
            b[ks] = *(const bf16x8*)(Wp + ks * 32);
#pragma unroll
        for (int mt = 0; mt < 2; mt++) {
            f32x4 c = acc[mt][nt];
#pragma unroll
            for (int ks = 0; ks < 4; ks++)
                c = __builtin_amdgcn_mfma_f32_16x16x32_bf16(a[mt][ks], b[ks], c, 0, 0, 0);
            acc[mt][nt] = c;
        }
    }

    int rbase = R0 + wv * 32 + quad * 4;
#pragma unroll
    for (int mt = 0; mt < 2; mt++)
#pragma unroll
        for (int nt = 0; nt < 8; nt++) {
            int col = nt * 16 + lm;
#pragma unroll
            for (int reg = 0; reg < 4; reg++) {
                int r = rbase + mt * 16 + reg;
                if (r < N_NODES) {
                    float v = acc[mt][nt][reg];
                    if (col < 64)
                        out[(size_t)r * 64 + col] = v + bmu[col];
                    else
                        out[(size_t)N_NODES * 64 + (size_t)r * 64 + (col - 64)] = v + bls[col - 64];
                }
            }
        }
}

// ---------------- launch ----------------

extern "C" void kernel_launch(void* const* d_in, const int* in_sizes, int n_in,
                              void* d_out, int out_size, void* d_ws, size_t ws_size,
                              hipStream_t stream) {
    const float* x    = (const float*)d_in[0];
    const int*   ei   = (const int*)d_in[1];
    const float* W1   = (const float*)d_in[2];
    const float* b1   = (const float*)d_in[3];
    const float* Wmu  = (const float*)d_in[4];
    const float* bmu  = (const float*)d_in[5];
    const float* Wls  = (const float*)d_in[6];
    const float* bls  = (const float*)d_in[7];
    const int* src = ei;
    const int* dst = ei + N_EDGES;

    char* p = (char*)d_ws;
    unsigned short* bufA = (unsigned short*)p; p += (size_t)N_NODES * 128 * 2; // h0' sliced; later g node-major
    unsigned short* bufH = (unsigned short*)p; p += (size_t)N_NODES * 128 * 2; // hb' sliced
    unsigned short* Wt1  = (unsigned short*)p; p += 128 * 128 * 2;
    unsigned short* WtC  = (unsigned short*)p; p += 128 * 128 * 2;
    int*   Cm      = (int*)p;   p += (size_t)NBLK * NB * 4;
    int*   bktSum  = (int*)p;   p += 256 * 4;
    int*   bktBase = (int*)p;   p += 256 * 4;
    int*   rowptr  = (int*)p;   p += 400016;
    float* dinv    = (float*)p; p += 400000;
    unsigned int* bucketed = (unsigned int*)p; p += (size_t)N_EDGES * 4;
    int*   csr_src = (int*)p;   p += (size_t)N_EDGES * 4;
    int*   ctr     = (int*)p;   p += 64 * 4;

    // CSR build
    k_phaseA<<<NBLK, 256, 0, stream>>>(dst, Cm);
    k_scanBkt<<<NB, 256, 0, stream>>>(Cm, bktSum);
    k_scanBase<<<1, 256, 0, stream>>>(bktSum, bktBase);
    k_phaseB<<<NBLK, 256, 0, stream>>>(src, dst, Cm, bktBase, bucketed);
    k_phaseC<<<NB, 512, 0, stream>>>(bucketed, bktBase, rowptr, dinv, csr_src);

    k_prepW<<<64, 256, 0, stream>>>(W1, Wmu, Wls, Wt1, WtC, ctr);

    int gblk = (N_NODES + 127) / 128;   // 782

    // layer 1: h0' = dinv*(x@W1) (sliced) ; hb' = dinv*relu(dinv*agg+b1) (sliced)
    k_gemm1<<<gblk, 256, 0, stream>>>(x, Wt1, dinv, bufA);
    k_aggx<1><<<2048, 256, 0, stream>>>(bufA, rowptr, csr_src, dinv, b1, bufH, ctr);

    // layer 2: g = dinv*(self+sum hb') (node-major) ; out = g @ [Wmu|Wls] + bias
    k_aggx<2><<<2048, 256, 0, stream>>>(bufH, rowptr, csr_src, dinv, b1, bufA, ctr);
    k_gemm2<<<gblk, 256, 0, stream>>>(bufA, WtC, bmu, bls, (float*)d_out);
}